// Round 5
// baseline (100.275 us; speedup 1.0000x reference)
//
#include <hip/hip_runtime.h>

// Problem constants: B=16, MAX_LEN=100, LOC_MAX=20000, EMB=256, D_DELTA=2
#define NB 16
#define MLEN 100
#define EMBD 256
#define LMAX 20000
#define NLT 157            // l-tiles of 128 (157*128 = 20096)
#define NT16 1256          // n-tiles of 16  (NLT*8)
#define NKS 8              // K=256 / 32
#define NBFRAG (NT16 * NKS)      // 10048 B-fragments (64 lanes x 16B each)
#define NAFRAG (NB * NKS * 7)    // 896 A-fragments, layout [b][ks][mt]
#define BTASKS (NBFRAG * 64)     // 643072
#define ATASKS (NAFRAG * 64)     // 57344
#define PREP_BLOCKS ((BTASKS + ATASKS) / 256)  // 2736 exactly
#define PPITCH 130               // P row pitch (floats): even (8B align), 2-way read alias = free

typedef __attribute__((ext_vector_type(4))) float f32x4;
typedef __attribute__((ext_vector_type(8))) short bf16x8;
typedef const __attribute__((address_space(1))) unsigned int* as1_u32p;
typedef __attribute__((address_space(3))) unsigned int* as3_u32p;

__device__ __forceinline__ unsigned short f2bf(float x) {
    union { float f; unsigned u; } a; a.f = x;
    unsigned r = a.u + 0x7FFFu + ((a.u >> 16) & 1u);
    return (unsigned short)(r >> 16);
}
__device__ __forceinline__ float bf2f(unsigned short h) {
    union { unsigned u; float f; } a; a.u = ((unsigned)h) << 16;
    return a.f;
}

__device__ __forceinline__ void split8(f32x4 v0, f32x4 v1, float w, uint4& hi, uint4& lo) {
    float x[8] = { v0[0]*w, v0[1]*w, v0[2]*w, v0[3]*w, v1[0]*w, v1[1]*w, v1[2]*w, v1[3]*w };
    unsigned h[8], l[8];
    #pragma unroll
    for (int j = 0; j < 8; ++j) {
        unsigned short hh = f2bf(x[j]);
        h[j] = hh;
        l[j] = f2bf(x[j] - bf2f(hh));
    }
    hi = make_uint4(h[0] | (h[1] << 16), h[2] | (h[3] << 16), h[4] | (h[5] << 16), h[6] | (h[7] << 16));
    lo = make_uint4(l[0] | (l[1] << 16), l[2] | (l[3] << 16), l[4] | (l[5] << 16), l[6] | (l[7] << 16));
}

// ---------------- Kernel 1: one-time conversion + MFMA-fragment packing ----------------
// B frag f = t16*NKS+ks : emb_cand[t16*16 + (lane&15)][ks*32 + (lane>>4)*8 ..+8]
// A frag f = (b*NKS+ks)*7+mt : vw[m]*attn[b][m][..], m = mt*16 + (lane&15)   (ks-major)
__global__ __launch_bounds__(256)
void prep_kernel(const float* __restrict__ attn, const float* __restrict__ embt,
                 const float* __restrict__ vw,
                 unsigned short* __restrict__ Bhi, unsigned short* __restrict__ Blo,
                 unsigned short* __restrict__ Ahi, unsigned short* __restrict__ Alo) {
    const int gid = blockIdx.x * 256 + threadIdx.x;
    if (gid < BTASKS) {
        const int lane = gid & 63;
        const int f    = gid >> 6;
        const int ks   = f & 7;
        const int t16  = f >> 3;
        const int n    = t16 * 16 + (lane & 15);
        const int k    = ks * 32 + (lane >> 4) * 8;
        f32x4 v0 = {0.f,0.f,0.f,0.f}, v1 = {0.f,0.f,0.f,0.f};
        if (n < LMAX) {
            const float* p = embt + (size_t)(n + 1) * EMBD + k;
            v0 = *reinterpret_cast<const f32x4*>(p);
            v1 = *reinterpret_cast<const f32x4*>(p + 4);
        }
        uint4 hi, lo;
        split8(v0, v1, 1.f, hi, lo);
        reinterpret_cast<uint4*>(Bhi)[gid] = hi;
        reinterpret_cast<uint4*>(Blo)[gid] = lo;
    } else {
        const int gid2 = gid - BTASKS;
        const int lane = gid2 & 63;
        const int f    = gid2 >> 6;     // (b*NKS+ks)*7 + mt
        const int mt   = f % 7;
        const int t    = f / 7;
        const int ks   = t & 7;
        const int b    = t >> 3;
        const int m    = mt * 16 + (lane & 15);
        const int k    = ks * 32 + (lane >> 4) * 8;
        f32x4 v0 = {0.f,0.f,0.f,0.f}, v1 = {0.f,0.f,0.f,0.f};
        float w = 0.f;
        if (m < MLEN) {
            w = vw[m];
            const float* p = attn + ((size_t)b * MLEN + m) * EMBD + k;
            v0 = *reinterpret_cast<const f32x4*>(p);
            v1 = *reinterpret_cast<const f32x4*>(p + 4);
        }
        uint4 hi, lo;
        split8(v0, v1, w, hi, lo);
        reinterpret_cast<uint4*>(Ahi)[gid2] = hi;
        reinterpret_cast<uint4*>(Alo)[gid2] = lo;
    }
}

// ---------------- Kernel 2: LDS-staged pipelined GEMM + P-park + batched sdelta stream ----------------
struct GemmLds { unsigned short Alds[2 * 14 * 512]; };              // 28672 B
struct StreamLds { float P2[MLEN * PPITCH]; float red[4 * 128]; };  // 52000 + 2048 = 54048 B
union LdsU { GemmLds g; StreamLds s; };

__global__ __launch_bounds__(256, 3)
void main_kernel(const unsigned short* __restrict__ Bhi, const unsigned short* __restrict__ Blo,
                 const unsigned short* __restrict__ Ahi, const unsigned short* __restrict__ Alo,
                 const float* __restrict__ sdelta, float* __restrict__ out) {
    __shared__ __align__(16) LdsU u;
    const int b    = blockIdx.x;
    const int lt   = blockIdx.y;
    const int w    = threadIdx.x >> 6;
    const int lane = threadIdx.x & 63;
    const int llo  = lane & 15;
    const int lhi  = lane >> 4;

    f32x4 acc[7][2];
    #pragma unroll
    for (int i = 0; i < 7; ++i) {
        acc[i][0] = (f32x4){0.f,0.f,0.f,0.f};
        acc[i][1] = (f32x4){0.f,0.f,0.f,0.f};
    }

    // async-stage A[b][ks] (14 frags: u<7 -> hi[mt=u], u>=7 -> lo[mt=u-7]) into Alds buf
    auto stageA = [&](int ks, int buf) {
        #pragma unroll
        for (int j = 0; j < 4; ++j) {
            const int uu = j * 4 + w;          // wave-uniform
            if (uu < 14) {
                const int mt = (uu < 7) ? uu : uu - 7;
                const unsigned short* base = (uu < 7) ? Ahi : Alo;
                const unsigned short* src = base + ((size_t)((b * NKS + ks) * 7 + mt)) * 512 + lane * 8;
                unsigned short* dst = &u.g.Alds[buf * 7168 + uu * 512];  // uniform base; HW adds lane*16B
                __builtin_amdgcn_global_load_lds((as1_u32p)(const void*)src,
                                                 (as3_u32p)(void*)dst, 16, 0, 0);
            }
        }
    };
    const int t16b = lt * 8 + w * 2;
    auto loadB = [&](int ks, bf16x8* dst) {
        const size_t bo0 = ((size_t)((t16b + 0) * NKS + ks) * 64 + lane) * 8;
        const size_t bo1 = ((size_t)((t16b + 1) * NKS + ks) * 64 + lane) * 8;
        dst[0] = *reinterpret_cast<const bf16x8*>(Bhi + bo0);
        dst[1] = *reinterpret_cast<const bf16x8*>(Blo + bo0);
        dst[2] = *reinterpret_cast<const bf16x8*>(Bhi + bo1);
        dst[3] = *reinterpret_cast<const bf16x8*>(Blo + bo1);
    };

    bf16x8 Bc[4], Bn[4];
    stageA(0, 0);
    loadB(0, Bc);
    __syncthreads();

    #pragma unroll
    for (int ks = 0; ks < NKS; ++ks) {
        if (ks + 1 < NKS) {
            stageA(ks + 1, (ks + 1) & 1);     // async into other buffer
            loadB(ks + 1, Bn);                // in-flight across the MFMA cluster
        }
        #pragma unroll
        for (int mt = 0; mt < 7; ++mt) {
            const bf16x8 ah = *reinterpret_cast<const bf16x8*>(&u.g.Alds[(ks & 1) * 7168 + mt * 512 + lane * 8]);
            const bf16x8 al = *reinterpret_cast<const bf16x8*>(&u.g.Alds[(ks & 1) * 7168 + (7 + mt) * 512 + lane * 8]);
            acc[mt][0] = __builtin_amdgcn_mfma_f32_16x16x32_bf16(ah, Bc[0], acc[mt][0], 0, 0, 0);
            acc[mt][1] = __builtin_amdgcn_mfma_f32_16x16x32_bf16(ah, Bc[2], acc[mt][1], 0, 0, 0);
            acc[mt][0] = __builtin_amdgcn_mfma_f32_16x16x32_bf16(ah, Bc[1], acc[mt][0], 0, 0, 0);
            acc[mt][1] = __builtin_amdgcn_mfma_f32_16x16x32_bf16(ah, Bc[3], acc[mt][1], 0, 0, 0);
            acc[mt][0] = __builtin_amdgcn_mfma_f32_16x16x32_bf16(al, Bc[0], acc[mt][0], 0, 0, 0);
            acc[mt][1] = __builtin_amdgcn_mfma_f32_16x16x32_bf16(al, Bc[2], acc[mt][1], 0, 0, 0);
        }
        __syncthreads();   // drains vmcnt (stage+Bn); also protects Alds before P-park overwrite at ks=7
        if (ks + 1 < NKS) { Bc[0] = Bn[0]; Bc[1] = Bn[1]; Bc[2] = Bn[2]; Bc[3] = Bn[3]; }
    }

    // ---------------- park P into LDS (acc dies here) ----------------
    // C/D layout: col = lane&15 (+nt*16), row m = mt*16 + (lane>>4)*4 + i  [verified r1-r4]
    #pragma unroll
    for (int mt = 0; mt < 7; ++mt) {
        #pragma unroll
        for (int nt = 0; nt < 2; ++nt) {
            const int col = w * 32 + nt * 16 + llo;
            #pragma unroll
            for (int i = 0; i < 4; ++i) {
                const int m = mt * 16 + lhi * 4 + i;
                if (m < MLEN) u.s.P2[m * PPITCH + col] = acc[mt][nt][i];
            }
        }
    }

    // ---------------- issue ALL 25 sdelta float4 loads back-to-back (batched MLP) ----------------
    const int lp = 2 * lane;                       // tile-local l pair
    const int l0 = lt * 128 + lp;                  // global l of first elem
    const float msk0 = (l0     < LMAX) ? 1.f : 0.f;
    const float msk1 = (l0 + 1 < LMAX) ? 1.f : 0.f;
    const int lsafe  = (l0 + 1 < LMAX) ? l0 : (LMAX - 2);
    const float* sdb = sdelta + ((size_t)(b * MLEN) * LMAX + lsafe) * 2;

    f32x4 v[25];
    #pragma unroll
    for (int i = 0; i < 25; ++i) {
        const int m = w + 4 * i;
        v[i] = *reinterpret_cast<const f32x4*>(sdb + (size_t)m * (LMAX * 2));
    }
    __builtin_amdgcn_sched_barrier(0);   // loads must all issue before anything below
    __syncthreads();                      // single vmcnt(0) drain: all 25 loads fly in parallel

    float accE = 0.f, accO = 0.f;
    #pragma unroll
    for (int i = 0; i < 25; ++i) {
        const int m = w + 4 * i;
        const float2 p = *reinterpret_cast<const float2*>(&u.s.P2[m * PPITCH + lp]);
        accE += (v[i][0] + v[i][1]) * p.x;
        accO += (v[i][2] + v[i][3]) * p.y;
    }
    *reinterpret_cast<float2*>(&u.s.red[w * 128 + lp]) = make_float2(accE * msk0, accO * msk1);
    __syncthreads();
    if (threadIdx.x < 128) {
        const int l = lt * 128 + threadIdx.x;
        if (l < LMAX) {
            const int t = threadIdx.x;
            float s = u.s.red[t] + u.s.red[128 + t] + u.s.red[256 + t] + u.s.red[384 + t];
            out[(size_t)b * LMAX + l] = s;
        }
    }
}

// ---------------- Fallback (ws too small): straightforward f32 compute ----------------
__global__ __launch_bounds__(256)
void fallback_kernel(const float* __restrict__ attn, const float* __restrict__ sdelta,
                     const float* __restrict__ embt, const float* __restrict__ vw,
                     float* __restrict__ out) {
    const int idx = blockIdx.x * 256 + threadIdx.x;
    if (idx >= NB * LMAX) return;
    const int b = idx / LMAX;
    const int l = idx % LMAX;
    float s = 0.f;
    for (int m = 0; m < MLEN; ++m) {
        const float* ar = attn + ((size_t)b * MLEN + m) * EMBD;
        const float* er = embt + (size_t)(l + 1) * EMBD;
        float dot = 0.f;
        for (int e = 0; e < EMBD; ++e) dot += ar[e] * er[e];
        const size_t so = (((size_t)b * MLEN + m) * LMAX + l) * 2;
        s += dot * vw[m] * (sdelta[so] + sdelta[so + 1]);
    }
    out[idx] = s;
}

extern "C" void kernel_launch(void* const* d_in, const int* in_sizes, int n_in,
                              void* d_out, int out_size, void* d_ws, size_t ws_size,
                              hipStream_t stream) {
    const float* attn   = (const float*)d_in[0];  // [16][100][256] f32
    const float* sdelta = (const float*)d_in[1];  // [16][100][20000][2] f32
    // d_in[2] = traj_len — unused by the reference computation
    const float* embt   = (const float*)d_in[3];  // [20001][256] f32
    const float* vw     = (const float*)d_in[4];  // [1][100] f32
    float* out = (float*)d_out;                   // [16][20000] f32

    const size_t bfragShorts = (size_t)NBFRAG * 512;  // 5,144,576
    const size_t afragShorts = (size_t)NAFRAG * 512;  //   458,752
    const size_t needed = (2 * bfragShorts + 2 * afragShorts) * sizeof(unsigned short); // 22,413,312 B

    if (ws_size >= needed) {
        unsigned short* Bhi = (unsigned short*)d_ws;
        unsigned short* Blo = Bhi + bfragShorts;
        unsigned short* Ahi = Blo + bfragShorts;
        unsigned short* Alo = Ahi + afragShorts;
        prep_kernel<<<PREP_BLOCKS, 256, 0, stream>>>(attn, embt, vw, Bhi, Blo, Ahi, Alo);
        main_kernel<<<dim3(NB, NLT), 256, 0, stream>>>(Bhi, Blo, Ahi, Alo, sdelta, out);
    } else {
        fallback_kernel<<<(NB * LMAX + 255) / 256, 256, 0, stream>>>(attn, sdelta, embt, vw, out);
    }
}